// Round 1
// baseline (7723.698 us; speedup 1.0000x reference)
//
#include <hip/hip_runtime.h>
#include <math.h>

#define BN 32768
#define DN 256
#define KN 8192

// Output layout (floats, concatenated in reference return order)
#define O_LOSS 8388608       // BN*DN
#define O_IDX  8388609
#define O_PERP 8421377       // O_IDX + BN
#define O_EMB  8421378
#define O_CS   10518530      // O_EMB + KN*DN
#define O_ES   10526722      // O_CS + KN

// ws layout (floats): [0]=loss_acc [1]=n_acc [2]=plog_acc [3..7] pad
// [8 .. 8+BN) idx (int), then cluster[KN], embsum[KN*DN], newcs[KN], enorm[KN]

__device__ __forceinline__ float wave_reduce_add(float v) {
#pragma unroll
  for (int off = 32; off > 0; off >>= 1) v += __shfl_down(v, off);
  return v;
}

__global__ __launch_bounds__(256) void k_enorm(const float* __restrict__ emb,
                                               float* __restrict__ enorm) {
  int wid = threadIdx.x >> 6, lane = threadIdx.x & 63;
  int row = blockIdx.x * 4 + wid;
  float4 v = *(const float4*)(emb + (size_t)row * DN + (lane << 2));
  float s = v.x * v.x + v.y * v.y + v.z * v.z + v.w * v.w;
  s = wave_reduce_add(s);
  if (lane == 0) enorm[row] = s;
}

// 64 rows/block, 256 threads, 4x4 register tile per thread.
// Z resident in LDS (64KB, XOR-swizzled at float4 granularity: conflict-free),
// E streamed from global (L2-resident, 8MB).
__global__ __launch_bounds__(256) void k_argmin(const float* __restrict__ z,
                                                const float* __restrict__ emb,
                                                const float* __restrict__ enorm,
                                                int* __restrict__ idx_i,
                                                float* __restrict__ idx_f) {
  __shared__ float Zs[64 * 256];
  const int tid = threadIdx.x;
  const int row0 = blockIdx.x * 64;
#pragma unroll
  for (int it = 0; it < 16; ++it) {
    int li = it * 256 + tid;
    int r = li >> 6;
    int c4 = (li & 63) << 2;
    float4 v = *(const float4*)(z + (size_t)(row0 + r) * DN + c4);
    *(float4*)(Zs + r * 256 + (c4 ^ ((r & 15) << 2))) = v;
  }
  __syncthreads();

  const int tr = tid >> 4;   // 0..15 -> rows tr, tr+16, tr+32, tr+48
  const int tc = tid & 15;   // cols (within 64-chunk): tc, tc+16, tc+32, tc+48
  const int xo = tr << 2;    // LDS swizzle offset (bytes/4) for this thread's rows
  const float* zb = Zs + tr * 256;

  float best[4];
  int bidx[4];
#pragma unroll
  for (int i = 0; i < 4; ++i) { best[i] = 3.4e38f; bidx[i] = 0; }

  for (int kc = 0; kc < KN; kc += 64) {
    const float* e0 = emb + (size_t)(kc + tc) * DN;
    float acc[4][4];
#pragma unroll
    for (int i = 0; i < 4; ++i)
#pragma unroll
      for (int j = 0; j < 4; ++j) acc[i][j] = 0.f;

    for (int kk = 0; kk < 256; kk += 4) {
      int kx = kk ^ xo;
      float4 a[4], b[4];
      a[0] = *(const float4*)(zb + kx);
      a[1] = *(const float4*)(zb + 16 * 256 + kx);
      a[2] = *(const float4*)(zb + 32 * 256 + kx);
      a[3] = *(const float4*)(zb + 48 * 256 + kx);
      b[0] = *(const float4*)(e0 + kk);
      b[1] = *(const float4*)(e0 + 16 * DN + kk);
      b[2] = *(const float4*)(e0 + 32 * DN + kk);
      b[3] = *(const float4*)(e0 + 48 * DN + kk);
#pragma unroll
      for (int i = 0; i < 4; ++i)
#pragma unroll
        for (int j = 0; j < 4; ++j)
          acc[i][j] += a[i].x * b[j].x + a[i].y * b[j].y +
                       a[i].z * b[j].z + a[i].w * b[j].w;
    }

#pragma unroll
    for (int j = 0; j < 4; ++j) {
      int c = kc + tc + 16 * j;
      float en = enorm[c];
#pragma unroll
      for (int i = 0; i < 4; ++i) {
        float d = en - 2.f * acc[i][j];
        if (d < best[i] || (d == best[i] && c < bidx[i])) {
          best[i] = d;
          bidx[i] = c;
        }
      }
    }
  }

  // cross-thread (tc) reduction per row, via LDS (reuse Zs)
  __syncthreads();
  float* redv = Zs;                 // 64*16 floats
  int* redi = (int*)(Zs + 1024);    // 64*16 ints
#pragma unroll
  for (int i = 0; i < 4; ++i) {
    int r = tr + 16 * i;
    redv[r * 16 + tc] = best[i];
    redi[r * 16 + tc] = bidx[i];
  }
  __syncthreads();
  if (tid < 64) {
    float bv = redv[tid * 16];
    int bi = redi[tid * 16];
#pragma unroll
    for (int t = 1; t < 16; ++t) {
      float v = redv[tid * 16 + t];
      int ii = redi[tid * 16 + t];
      if (v < bv || (v == bv && ii < bi)) { bv = v; bi = ii; }
    }
    idx_i[row0 + tid] = bi;
    idx_f[row0 + tid] = (float)bi;
  }
}

// one wave per row: gather z_q, write straight-through out, accumulate loss,
// cluster counts and embedding sums (atomics; avg 4 rows/code -> low contention)
__global__ __launch_bounds__(256) void k_gather(const float* __restrict__ z,
                                                const float* __restrict__ emb,
                                                const int* __restrict__ idx,
                                                float* __restrict__ out_zq,
                                                float* __restrict__ W,
                                                float* __restrict__ cluster,
                                                float* __restrict__ embsum) {
  int wid = threadIdx.x >> 6, lane = threadIdx.x & 63;
  int row = blockIdx.x * 4 + wid;
  int k = idx[row];
  int d = lane << 2;
  float4 zv = *(const float4*)(z + (size_t)row * DN + d);
  float4 ev = *(const float4*)(emb + (size_t)k * DN + d);
  float4 df = make_float4(ev.x - zv.x, ev.y - zv.y, ev.z - zv.z, ev.w - zv.w);
  float4 st = make_float4(zv.x + df.x, zv.y + df.y, zv.z + df.z, zv.w + df.w);
  *(float4*)(out_zq + (size_t)row * DN + d) = st;
  float sq = df.x * df.x + df.y * df.y + df.z * df.z + df.w * df.w;
  sq = wave_reduce_add(sq);
  if (lane == 0) {
    unsafeAtomicAdd(&W[0], sq);
    unsafeAtomicAdd(&cluster[k], 1.0f);
  }
  float* es = embsum + (size_t)k * DN + d;
  unsafeAtomicAdd(es + 0, zv.x);
  unsafeAtomicAdd(es + 1, zv.y);
  unsafeAtomicAdd(es + 2, zv.z);
  unsafeAtomicAdd(es + 3, zv.w);
}

// per-code EMA cluster size + global sums (n, sum p*log p)
__global__ __launch_bounds__(256) void k_ema(const float* __restrict__ ema_cs,
                                             const float* __restrict__ cluster,
                                             float* __restrict__ newcs,
                                             float* __restrict__ W) {
  int k = blockIdx.x * 256 + threadIdx.x;
  float cs = cluster[k];
  float nc = 0.99f * ema_cs[k] + 0.01f * cs;
  newcs[k] = nc;
  float p = cs * (1.0f / 32768.0f);
  float pl = p * logf(p + 1e-10f);
  float s1 = wave_reduce_add(nc);
  float s2 = wave_reduce_add(pl);
  __shared__ float a1[4], a2[4];
  int wid = threadIdx.x >> 6, lane = threadIdx.x & 63;
  if (lane == 0) { a1[wid] = s1; a2[wid] = s2; }
  __syncthreads();
  if (threadIdx.x == 0) {
    unsafeAtomicAdd(&W[1], a1[0] + a1[1] + a1[2] + a1[3]);
    unsafeAtomicAdd(&W[2], a2[0] + a2[1] + a2[2] + a2[3]);
  }
}

__global__ __launch_bounds__(256) void k_final(const float* __restrict__ z,
                                               const float* __restrict__ ema_es,
                                               const float* __restrict__ noise,
                                               const int* __restrict__ ridx,
                                               const float* __restrict__ embsum,
                                               const float* __restrict__ newcs,
                                               const float* __restrict__ W,
                                               float* __restrict__ out) {
  int gid = blockIdx.x * 256 + threadIdx.x;   // 0 .. KN*64-1
  int k = gid >> 6;
  int d = (gid & 63) << 2;
  float n = W[1];
  float nc = newcs[k];
  float cs_sm = (nc + 1e-5f) / (n + (float)KN * 1e-5f) * n;
  bool dead = (nc / n) < (1.0f / (KN * 10.0f));
  size_t o = (size_t)k * DN + d;
  float4 es = *(const float4*)(ema_es + o);
  float4 s = *(const float4*)(embsum + o);
  float4 nes = make_float4(0.99f * es.x + 0.01f * s.x, 0.99f * es.y + 0.01f * s.y,
                           0.99f * es.z + 0.01f * s.z, 0.99f * es.w + 0.01f * s.w);
  float4 ne = make_float4(nes.x / cs_sm, nes.y / cs_sm, nes.z / cs_sm, nes.w / cs_sm);
  if (dead) {  // wave-uniform branch (one k per wave)
    int r = ridx[k];
    float4 rz = *(const float4*)(z + (size_t)r * DN + d);
    float4 rn = *(const float4*)(noise + o);
    nes = make_float4(rz.x + rn.x, rz.y + rn.y, rz.z + rn.z, rz.w + rn.w);
    ne = nes;
  }
  // output bases are 2-float aligned only -> float2 stores
  float* oe = out + O_EMB + o;
  *(float2*)(oe) = make_float2(ne.x, ne.y);
  *(float2*)(oe + 2) = make_float2(ne.z, ne.w);
  float* os = out + O_ES + o;
  *(float2*)(os) = make_float2(nes.x, nes.y);
  *(float2*)(os + 2) = make_float2(nes.z, nes.w);
  if ((gid & 63) == 0) out[O_CS + k] = dead ? 1.0f : nc;
  if (gid == 0) {
    out[O_LOSS] = 0.25f * W[0] * (1.0f / 8388608.0f);
    out[O_PERP] = expf(-W[2]);
  }
}

extern "C" void kernel_launch(void* const* d_in, const int* in_sizes, int n_in,
                              void* d_out, int out_size, void* d_ws, size_t ws_size,
                              hipStream_t stream) {
  const float* z = (const float*)d_in[0];
  const float* emb = (const float*)d_in[1];
  const float* ema_cs = (const float*)d_in[2];
  const float* ema_es = (const float*)d_in[3];
  const float* noise = (const float*)d_in[4];
  const int* ridx = (const int*)d_in[5];
  float* out = (float*)d_out;

  float* W = (float*)d_ws;
  int* idxp = (int*)(W + 8);
  float* cluster = W + 8 + BN;
  float* embsum = cluster + KN;
  float* newcs = embsum + (size_t)KN * DN;
  float* enorm = newcs + KN;

  // zero scalars + idx + cluster + embsum (harness poisons ws with 0xAA)
  hipMemsetAsync(d_ws, 0, (size_t)(8 + BN + KN + (size_t)KN * DN) * sizeof(float),
                 stream);

  k_enorm<<<KN / 4, 256, 0, stream>>>(emb, enorm);
  k_argmin<<<BN / 64, 256, 0, stream>>>(z, emb, enorm, idxp, out + O_IDX);
  k_gather<<<BN / 4, 256, 0, stream>>>(z, emb, idxp, out, W, cluster, embsum);
  k_ema<<<KN / 256, 256, 0, stream>>>(ema_cs, cluster, newcs, W);
  k_final<<<(KN * 64) / 256, 256, 0, stream>>>(z, ema_es, noise, ridx, embsum,
                                               newcs, W, out);
}

// Round 2
// 1571.920 us; speedup vs baseline: 4.9135x; 4.9135x over previous
//
#include <hip/hip_runtime.h>
#include <math.h>

#define BN 32768
#define DN 256
#define KN 8192

// Output layout (floats, concatenated in reference return order)
#define O_LOSS 8388608       // BN*DN
#define O_IDX  8388609
#define O_PERP 8421377       // O_IDX + BN
#define O_EMB  8421378
#define O_CS   10518530      // O_EMB + KN*DN
#define O_ES   10526722      // O_CS + KN

typedef _Float16 half_t;
typedef __attribute__((ext_vector_type(4))) _Float16 half4v;
typedef __attribute__((ext_vector_type(8))) _Float16 half8;
typedef __attribute__((ext_vector_type(4))) float floatx4;
typedef unsigned long long u64;
typedef unsigned int u32;

__device__ __forceinline__ float wave_reduce_add(float v) {
#pragma unroll
  for (int off = 32; off > 0; off >>= 1) v += __shfl_down(v, off);
  return v;
}

// fp32 -> fp16 hi/lo planar split (4 elements/thread)
__global__ __launch_bounds__(256) void k_split(const float* __restrict__ x,
                                               half_t* __restrict__ hi,
                                               half_t* __restrict__ lo) {
  size_t i = ((size_t)blockIdx.x * 256 + threadIdx.x) * 4;
  float4 v = *(const float4*)(x + i);
  half4v h, l;
  h[0] = (half_t)v.x; l[0] = (half_t)(v.x - (float)h[0]);
  h[1] = (half_t)v.y; l[1] = (half_t)(v.y - (float)h[1]);
  h[2] = (half_t)v.z; l[2] = (half_t)(v.z - (float)h[2]);
  h[3] = (half_t)v.w; l[3] = (half_t)(v.w - (float)h[3]);
  *(half4v*)(hi + i) = h;
  *(half4v*)(lo + i) = l;
}

__global__ __launch_bounds__(256) void k_enorm(const float* __restrict__ emb,
                                               float* __restrict__ enorm) {
  int wid = threadIdx.x >> 6, lane = threadIdx.x & 63;
  int row = blockIdx.x * 4 + wid;
  float4 v = *(const float4*)(emb + (size_t)row * DN + (lane << 2));
  float s = v.x * v.x + v.y * v.y + v.z * v.z + v.w * v.w;
  s = wave_reduce_add(s);
  if (lane == 0) enorm[row] = s;
}

// MFMA distance-argmin. Split-fp16 (hi+lo, 3 products) == fp32-class accuracy.
// Block: 256 thr = 4 waves, tile 128 codes (M) x 128 zrows (N), BK=64, K=256.
// LDS kg-major layout: elem (m,k) at [k/8]*1024 + m*8 + k%8 (half units) --
// contiguous for global_load_lds lane*16B writes AND conflict-free for
// ds_read_b128 fragment reads (lanes stride 16B -> full bank coverage).
__global__ __launch_bounds__(256) void k_dist(const half_t* __restrict__ eh,
                                              const half_t* __restrict__ el,
                                              const half_t* __restrict__ zh,
                                              const half_t* __restrict__ zl,
                                              const float* __restrict__ enorm,
                                              u64* __restrict__ best) {
  __shared__ __align__(16) half_t L[4 * 8192];   // AH AL BH BL, 16KB each
  half_t* AH = L;
  half_t* AL = L + 8192;
  half_t* BH = L + 16384;
  half_t* BL = L + 24576;

  const int tid = threadIdx.x;
  const int wid = tid >> 6, lane = tid & 63;
  const int lane16 = lane & 15, quad = lane >> 4;
  const int bm0 = blockIdx.x * 128;   // codes
  const int bn0 = blockIdx.y * 128;   // z rows
  const int wm = (wid & 1) * 64;      // wave's 64x64 subtile
  const int wn = (wid >> 1) * 64;

  // each wave stages one of the 4 LDS arrays
  const half_t* gsrc;
  half_t* larr;
  if (wid == 0)      { gsrc = eh + (size_t)bm0 * DN; larr = AH; }
  else if (wid == 1) { gsrc = el + (size_t)bm0 * DN; larr = AL; }
  else if (wid == 2) { gsrc = zh + (size_t)bn0 * DN; larr = BH; }
  else               { gsrc = zl + (size_t)bn0 * DN; larr = BL; }

  floatx4 acc[4][4] = {};

  for (int c = 0; c < 4; ++c) {
    const int kc = c * 64;
    // stage: 16 global_load_lds x 16B per wave (64 rows x 16B per instr)
#pragma unroll
    for (int kg = 0; kg < 8; ++kg)
#pragma unroll
      for (int mh = 0; mh < 2; ++mh) {
        const half_t* g = gsrc + (size_t)(mh * 64 + lane) * DN + kc + kg * 8;
        half_t* d = larr + kg * 1024 + mh * 512 + lane * 8;
        __builtin_amdgcn_global_load_lds(
            (const __attribute__((address_space(1))) void*)g,
            (__attribute__((address_space(3))) void*)d, 16, 0, 0);
      }
    __syncthreads();

#pragma unroll
    for (int ks = 0; ks < 2; ++ks) {
      const int kgo = ks * 4 + quad;   // this lane's k-group (k = kgo*8..+8)
      half8 ah[4], al[4], bh[4], bl[4];
#pragma unroll
      for (int t = 0; t < 4; ++t) {
        const int m = wm + t * 16 + lane16;
        ah[t] = *(half8*)(AH + kgo * 1024 + m * 8);
        al[t] = *(half8*)(AL + kgo * 1024 + m * 8);
        const int n = wn + t * 16 + lane16;
        bh[t] = *(half8*)(BH + kgo * 1024 + n * 8);
        bl[t] = *(half8*)(BL + kgo * 1024 + n * 8);
      }
#pragma unroll
      for (int mi = 0; mi < 4; ++mi)
#pragma unroll
        for (int ni = 0; ni < 4; ++ni) {
          acc[mi][ni] = __builtin_amdgcn_mfma_f32_16x16x32_f16(
              ah[mi], bh[ni], acc[mi][ni], 0, 0, 0);
          acc[mi][ni] = __builtin_amdgcn_mfma_f32_16x16x32_f16(
              ah[mi], bl[ni], acc[mi][ni], 0, 0, 0);
          acc[mi][ni] = __builtin_amdgcn_mfma_f32_16x16x32_f16(
              al[mi], bh[ni], acc[mi][ni], 0, 0, 0);
        }
    }
    __syncthreads();
  }

  // epilogue: d = enorm[code] - 2*dot (z^2 constant per row, dropped).
  // pack orderable float bits | code, min within lane, butterfly over quads,
  // one global atomicMin per lane.
  u64 key[4];
#pragma unroll
  for (int ni = 0; ni < 4; ++ni) {
    u64 k = ~0ull;
#pragma unroll
    for (int mi = 0; mi < 4; ++mi)
#pragma unroll
      for (int r = 0; r < 4; ++r) {
        const int code = bm0 + wm + mi * 16 + quad * 4 + r;
        const float d = enorm[code] - 2.0f * acc[mi][ni][r];
        u32 fb = __float_as_uint(d);
        fb ^= (fb >> 31) ? 0xFFFFFFFFu : 0x80000000u;  // signed -> unsigned order
        const u64 kk = ((u64)fb << 32) | (u32)code;
        k = kk < k ? kk : k;
      }
    key[ni] = k;
  }
#pragma unroll
  for (int ni = 0; ni < 4; ++ni) {
    u64 o = __shfl_xor(key[ni], 16);
    key[ni] = o < key[ni] ? o : key[ni];
    o = __shfl_xor(key[ni], 32);
    key[ni] = o < key[ni] ? o : key[ni];
  }
  const u64 mykey = quad == 0 ? key[0] : quad == 1 ? key[1] : quad == 2 ? key[2] : key[3];
  const int zrow = bn0 + wn + quad * 16 + lane16;
  atomicMin(best + zrow, mykey);
}

__global__ __launch_bounds__(256) void k_index(const u64* __restrict__ best,
                                               int* __restrict__ idxp,
                                               float* __restrict__ out_idx) {
  int i = blockIdx.x * 256 + threadIdx.x;
  u32 code = (u32)(best[i] & 0xFFFFFFFFu);
  idxp[i] = (int)code;
  out_idx[i] = (float)code;
}

// one wave per row: gather z_q, straight-through out, loss, cluster, embsum
__global__ __launch_bounds__(256) void k_gather(const float* __restrict__ z,
                                                const float* __restrict__ emb,
                                                const int* __restrict__ idx,
                                                float* __restrict__ out_zq,
                                                float* __restrict__ W,
                                                float* __restrict__ cluster,
                                                float* __restrict__ embsum) {
  int wid = threadIdx.x >> 6, lane = threadIdx.x & 63;
  int row = blockIdx.x * 4 + wid;
  int k = idx[row];
  int d = lane << 2;
  float4 zv = *(const float4*)(z + (size_t)row * DN + d);
  float4 ev = *(const float4*)(emb + (size_t)k * DN + d);
  float4 df = make_float4(ev.x - zv.x, ev.y - zv.y, ev.z - zv.z, ev.w - zv.w);
  float4 st = make_float4(zv.x + df.x, zv.y + df.y, zv.z + df.z, zv.w + df.w);
  *(float4*)(out_zq + (size_t)row * DN + d) = st;
  float sq = df.x * df.x + df.y * df.y + df.z * df.z + df.w * df.w;
  sq = wave_reduce_add(sq);
  if (lane == 0) {
    unsafeAtomicAdd(&W[0], sq);
    unsafeAtomicAdd(&cluster[k], 1.0f);
  }
  float* es = embsum + (size_t)k * DN + d;
  unsafeAtomicAdd(es + 0, zv.x);
  unsafeAtomicAdd(es + 1, zv.y);
  unsafeAtomicAdd(es + 2, zv.z);
  unsafeAtomicAdd(es + 3, zv.w);
}

__global__ __launch_bounds__(256) void k_ema(const float* __restrict__ ema_cs,
                                             const float* __restrict__ cluster,
                                             float* __restrict__ newcs,
                                             float* __restrict__ W) {
  int k = blockIdx.x * 256 + threadIdx.x;
  float cs = cluster[k];
  float nc = 0.99f * ema_cs[k] + 0.01f * cs;
  newcs[k] = nc;
  float p = cs * (1.0f / 32768.0f);
  float pl = p * logf(p + 1e-10f);
  float s1 = wave_reduce_add(nc);
  float s2 = wave_reduce_add(pl);
  __shared__ float a1[4], a2[4];
  int wid = threadIdx.x >> 6, lane = threadIdx.x & 63;
  if (lane == 0) { a1[wid] = s1; a2[wid] = s2; }
  __syncthreads();
  if (threadIdx.x == 0) {
    unsafeAtomicAdd(&W[1], a1[0] + a1[1] + a1[2] + a1[3]);
    unsafeAtomicAdd(&W[2], a2[0] + a2[1] + a2[2] + a2[3]);
  }
}

__global__ __launch_bounds__(256) void k_final(const float* __restrict__ z,
                                               const float* __restrict__ ema_es,
                                               const float* __restrict__ noise,
                                               const int* __restrict__ ridx,
                                               const float* __restrict__ embsum,
                                               const float* __restrict__ newcs,
                                               const float* __restrict__ W,
                                               float* __restrict__ out) {
  int gid = blockIdx.x * 256 + threadIdx.x;   // 0 .. KN*64-1
  int k = gid >> 6;
  int d = (gid & 63) << 2;
  float n = W[1];
  float nc = newcs[k];
  float cs_sm = (nc + 1e-5f) / (n + (float)KN * 1e-5f) * n;
  bool dead = (nc / n) < (1.0f / (KN * 10.0f));
  size_t o = (size_t)k * DN + d;
  float4 es = *(const float4*)(ema_es + o);
  float4 s = *(const float4*)(embsum + o);
  float4 nes = make_float4(0.99f * es.x + 0.01f * s.x, 0.99f * es.y + 0.01f * s.y,
                           0.99f * es.z + 0.01f * s.z, 0.99f * es.w + 0.01f * s.w);
  float4 ne = make_float4(nes.x / cs_sm, nes.y / cs_sm, nes.z / cs_sm, nes.w / cs_sm);
  if (dead) {  // wave-uniform (one k per wave)
    int r = ridx[k];
    float4 rz = *(const float4*)(z + (size_t)r * DN + d);
    float4 rn = *(const float4*)(noise + o);
    nes = make_float4(rz.x + rn.x, rz.y + rn.y, rz.z + rn.z, rz.w + rn.w);
    ne = nes;
  }
  float* oe = out + O_EMB + o;   // 8B-aligned region -> float2 stores
  *(float2*)(oe) = make_float2(ne.x, ne.y);
  *(float2*)(oe + 2) = make_float2(ne.z, ne.w);
  float* os = out + O_ES + o;
  *(float2*)(os) = make_float2(nes.x, nes.y);
  *(float2*)(os + 2) = make_float2(nes.z, nes.w);
  if ((gid & 63) == 0) out[O_CS + k] = dead ? 1.0f : nc;
  if (gid == 0) {
    out[O_LOSS] = 0.25f * W[0] * (1.0f / 8388608.0f);
    out[O_PERP] = expf(-W[2]);
  }
}

extern "C" void kernel_launch(void* const* d_in, const int* in_sizes, int n_in,
                              void* d_out, int out_size, void* d_ws, size_t ws_size,
                              hipStream_t stream) {
  const float* z = (const float*)d_in[0];
  const float* emb = (const float*)d_in[1];
  const float* ema_cs = (const float*)d_in[2];
  const float* ema_es = (const float*)d_in[3];
  const float* noise = (const float*)d_in[4];
  const int* ridx = (const int*)d_in[5];
  float* out = (float*)d_out;

  // ws layout
  float* W = (float*)d_ws;
  int* idxp = (int*)(W + 8);
  float* cluster = W + 8 + BN;
  float* embsum = cluster + KN;
  float* newcs = embsum + (size_t)KN * DN;
  float* enorm = newcs + KN;
  u64* best = (u64*)(enorm + KN);   // 8B-aligned (even float offset)

  // fp16 split scratch lives in d_out regions that are overwritten later:
  //  - z_q region [0, BN*DN) holds zh|zl (exactly BN*DN*4 bytes)
  //  - O_EMB region (+2 floats for 16B alignment) holds eh|el (spills 8B
  //    into O_CS, which k_final rewrites afterwards)
  half_t* zh = (half_t*)out;
  half_t* zl = zh + (size_t)BN * DN;
  half_t* eh = (half_t*)(out + O_EMB + 2);
  half_t* el = eh + (size_t)KN * DN;

  hipMemsetAsync(d_ws, 0,
                 (size_t)(8 + BN + KN + (size_t)KN * DN) * sizeof(float), stream);
  hipMemsetAsync(best, 0xFF, (size_t)BN * sizeof(u64), stream);

  k_split<<<(BN * DN) / 1024, 256, 0, stream>>>(z, zh, zl);
  k_split<<<(KN * DN) / 1024, 256, 0, stream>>>(emb, eh, el);
  k_enorm<<<KN / 4, 256, 0, stream>>>(emb, enorm);
  k_dist<<<dim3(KN / 128, BN / 128), 256, 0, stream>>>(eh, el, zh, zl, enorm, best);
  k_index<<<BN / 256, 256, 0, stream>>>(best, idxp, out + O_IDX);
  k_gather<<<BN / 4, 256, 0, stream>>>(z, emb, idxp, out, W, cluster, embsum);
  k_ema<<<KN / 256, 256, 0, stream>>>(ema_cs, cluster, newcs, W);
  k_final<<<(KN * 64) / 256, 256, 0, stream>>>(z, ema_es, noise, ridx, embsum,
                                               newcs, W, out);
}

// Round 3
// 1019.721 us; speedup vs baseline: 7.5743x; 1.5415x over previous
//
#include <hip/hip_runtime.h>
#include <math.h>

#define BN 32768
#define DN 256
#define KN 8192

// Output layout (floats, concatenated in reference return order)
#define O_LOSS 8388608       // BN*DN
#define O_IDX  8388609
#define O_PERP 8421377       // O_IDX + BN
#define O_EMB  8421378
#define O_CS   10518530      // O_EMB + KN*DN
#define O_ES   10526722      // O_CS + KN

typedef _Float16 half_t;
typedef __attribute__((ext_vector_type(8))) _Float16 half8;
typedef __attribute__((ext_vector_type(16))) float float16v;
typedef unsigned long long u64;
typedef unsigned int u32;

__device__ __forceinline__ float wave_reduce_add(float v) {
#pragma unroll
  for (int off = 32; off > 0; off >>= 1) v += __shfl_down(v, off);
  return v;
}

// fp32 -> fp16 hi/lo split, written in tile-packed layout:
//   [tile(128 rows)][kg = k/8 (32)][row%128][k%8]
// so k_dist staging is contiguous-1KB global_load_lds AND conflict-free
// fragment reads. Block = (tile t, kg-pair p); writes coalesced (contig 2KB),
// reads 32B @ 1KB stride (2x read amp, negligible).
__global__ __launch_bounds__(256) void k_split(const float* __restrict__ x,
                                               half_t* __restrict__ hi,
                                               half_t* __restrict__ lo) {
  const int t = blockIdx.x, p = blockIdx.y;
  const int sub = threadIdx.x >> 7, row = threadIdx.x & 127;
  const int kg = p * 2 + sub;
  const float* s = x + ((size_t)t * 128 + row) * 256 + kg * 8;
  float4 v0 = *(const float4*)s;
  float4 v1 = *(const float4*)(s + 4);
  float vv[8] = {v0.x, v0.y, v0.z, v0.w, v1.x, v1.y, v1.z, v1.w};
  half8 h, l;
#pragma unroll
  for (int i = 0; i < 8; ++i) {
    h[i] = (half_t)vv[i];
    l[i] = (half_t)(vv[i] - (float)h[i]);
  }
  size_t d = (size_t)t * 32768 + (size_t)kg * 1024 + (size_t)row * 8;
  *(half8*)(hi + d) = h;
  *(half8*)(lo + d) = l;
}

__global__ __launch_bounds__(256) void k_enorm(const float* __restrict__ emb,
                                               float* __restrict__ enorm) {
  int wid = threadIdx.x >> 6, lane = threadIdx.x & 63;
  int row = blockIdx.x * 4 + wid;
  float4 v = *(const float4*)(emb + (size_t)row * DN + (lane << 2));
  float s = v.x * v.x + v.y * v.y + v.z * v.z + v.w * v.w;
  s = wave_reduce_add(s);
  if (lane == 0) enorm[row] = s;
}

// MFMA 32x32x16 distance-argmin, split-fp16 (3 products), double-buffered.
// Block 128 codes x 128 z, 4 waves (wave = 64x64 = 2x2 frags), BK=32,
// LDS = 2 buffers x 4 arrays x 8KB = 64KB -> 2 blocks/CU.
// stage(c+1) issued before compute(c): loads in flight a full compute phase.
__global__ __launch_bounds__(256, 2) void k_dist(const half_t* __restrict__ eh,
                                                 const half_t* __restrict__ el,
                                                 const half_t* __restrict__ zh,
                                                 const half_t* __restrict__ zl,
                                                 const float* __restrict__ enorm,
                                                 u64* __restrict__ best) {
  __shared__ __align__(16) half_t L[2][4][4096];  // [buf][arr][kg4*1024+row*8]
  __shared__ float En[128];

  const int tid = threadIdx.x;
  const int wid = tid >> 6, lane = tid & 63;
  const int l31 = lane & 31, h = lane >> 5;
  const int bm0 = blockIdx.x * 128;  // codes
  const int bn0 = blockIdx.y * 128;  // z rows
  const int wm = (wid & 1) * 64, wn = (wid >> 1) * 64;

  if (tid < 128) En[tid] = enorm[bm0 + tid];

  // each wave stages one packed array; tile index = blockIdx.{x|y}
  const half_t* gsrc =
      wid == 0 ? eh + (size_t)blockIdx.x * 32768
    : wid == 1 ? el + (size_t)blockIdx.x * 32768
    : wid == 2 ? zh + (size_t)blockIdx.y * 32768
               : zl + (size_t)blockIdx.y * 32768;

  float16v acc[2][2] = {};

#define STAGE(c, b)                                                           \
  {                                                                           \
    const half_t* g_ = gsrc + (c) * 4096 + lane * 8;                          \
    half_t* d_ = &L[b][wid][lane * 8];                                        \
    _Pragma("unroll") for (int i_ = 0; i_ < 8; ++i_)                          \
        __builtin_amdgcn_global_load_lds(                                     \
            (const __attribute__((address_space(1))) void*)(g_ + i_ * 512),   \
            (__attribute__((address_space(3))) void*)(d_ + i_ * 512), 16, 0,  \
            0);                                                               \
  }

  STAGE(0, 0)
  for (int c = 0; c < 8; ++c) {
    __syncthreads();  // buffer c&1 staged; buffer (c+1)&1 fully consumed
    if (c < 7) STAGE(c + 1, (c + 1) & 1)
    const half_t* B0 = L[c & 1][0];
    const half_t* B1 = L[c & 1][1];
    const half_t* B2 = L[c & 1][2];
    const half_t* B3 = L[c & 1][3];
#pragma unroll
    for (int ks = 0; ks < 2; ++ks) {
      const int ko = (ks * 2 + h) * 1024;  // lane's k-group (8 halfs)
      half8 ahf[2], alf[2], bhf[2], blf[2];
#pragma unroll
      for (int i = 0; i < 2; ++i) {
        const int m = wm + i * 32 + l31;
        ahf[i] = *(const half8*)(B0 + ko + m * 8);
        alf[i] = *(const half8*)(B1 + ko + m * 8);
        const int n = wn + i * 32 + l31;
        bhf[i] = *(const half8*)(B2 + ko + n * 8);
        blf[i] = *(const half8*)(B3 + ko + n * 8);
      }
#pragma unroll
      for (int mi = 0; mi < 2; ++mi)
#pragma unroll
        for (int ni = 0; ni < 2; ++ni) {
          acc[mi][ni] = __builtin_amdgcn_mfma_f32_32x32x16_f16(
              ahf[mi], bhf[ni], acc[mi][ni], 0, 0, 0);
          acc[mi][ni] = __builtin_amdgcn_mfma_f32_32x32x16_f16(
              ahf[mi], blf[ni], acc[mi][ni], 0, 0, 0);
          acc[mi][ni] = __builtin_amdgcn_mfma_f32_32x32x16_f16(
              alf[mi], bhf[ni], acc[mi][ni], 0, 0, 0);
        }
    }
  }

  // epilogue: d = ||e||^2 - 2*dot (z^2 const per row). C/D layout 32x32:
  // col = lane&31 (z), row = (reg&3) + 8*(reg>>2) + 4*(lane>>5) (code).
  u64 key[2];
#pragma unroll
  for (int ni = 0; ni < 2; ++ni) {
    u64 kb = ~0ull;
#pragma unroll
    for (int mi = 0; mi < 2; ++mi)
#pragma unroll
      for (int r = 0; r < 16; ++r) {
        const int row = (r & 3) + 8 * (r >> 2) + 4 * h;
        const int lc = wm + mi * 32 + row;          // code within block
        const float d = En[lc] - 2.0f * acc[mi][ni][r];
        u32 fb = __float_as_uint(d);
        fb ^= (fb >> 31) ? 0xFFFFFFFFu : 0x80000000u;  // total order
        const u64 kk = ((u64)fb << 32) | (u32)(bm0 + lc);
        kb = kk < kb ? kk : kb;
      }
    key[ni] = kb;
  }
#pragma unroll
  for (int ni = 0; ni < 2; ++ni) {  // merge row-halves (h)
    u64 o = __shfl_xor(key[ni], 32);
    key[ni] = o < key[ni] ? o : key[ni];
  }
  const u64 mykey = h == 0 ? key[0] : key[1];
  const int zrow = bn0 + wn + h * 32 + l31;
  atomicMin(best + zrow, mykey);
}

// one wave per row: decode best, gather z_q, straight-through out, loss,
// cluster counts, embedding sums
__global__ __launch_bounds__(256) void k_gather(const float* __restrict__ z,
                                                const float* __restrict__ emb,
                                                const u64* __restrict__ best,
                                                float* __restrict__ out,
                                                float* __restrict__ W,
                                                float* __restrict__ cluster,
                                                float* __restrict__ embsum) {
  int wid = threadIdx.x >> 6, lane = threadIdx.x & 63;
  int row = blockIdx.x * 4 + wid;
  int k = (int)(u32)(best[row] & 0xFFFFFFFFu);
  int d = lane << 2;
  float4 zv = *(const float4*)(z + (size_t)row * DN + d);
  float4 ev = *(const float4*)(emb + (size_t)k * DN + d);
  float4 df = make_float4(ev.x - zv.x, ev.y - zv.y, ev.z - zv.z, ev.w - zv.w);
  float4 st = make_float4(zv.x + df.x, zv.y + df.y, zv.z + df.z, zv.w + df.w);
  *(float4*)(out + (size_t)row * DN + d) = st;
  float sq = df.x * df.x + df.y * df.y + df.z * df.z + df.w * df.w;
  sq = wave_reduce_add(sq);
  if (lane == 0) {
    unsafeAtomicAdd(&W[0], sq);
    unsafeAtomicAdd(&cluster[k], 1.0f);
    out[O_IDX + row] = (float)k;
  }
  float* es = embsum + (size_t)k * DN + d;
  unsafeAtomicAdd(es + 0, zv.x);
  unsafeAtomicAdd(es + 1, zv.y);
  unsafeAtomicAdd(es + 2, zv.z);
  unsafeAtomicAdd(es + 3, zv.w);
}

__global__ __launch_bounds__(256) void k_ema(const float* __restrict__ ema_cs,
                                             const float* __restrict__ cluster,
                                             float* __restrict__ newcs,
                                             float* __restrict__ W) {
  int k = blockIdx.x * 256 + threadIdx.x;
  float cs = cluster[k];
  float nc = 0.99f * ema_cs[k] + 0.01f * cs;
  newcs[k] = nc;
  float p = cs * (1.0f / 32768.0f);
  float pl = p * logf(p + 1e-10f);
  float s1 = wave_reduce_add(nc);
  float s2 = wave_reduce_add(pl);
  __shared__ float a1[4], a2[4];
  int wid = threadIdx.x >> 6, lane = threadIdx.x & 63;
  if (lane == 0) { a1[wid] = s1; a2[wid] = s2; }
  __syncthreads();
  if (threadIdx.x == 0) {
    unsafeAtomicAdd(&W[1], a1[0] + a1[1] + a1[2] + a1[3]);
    unsafeAtomicAdd(&W[2], a2[0] + a2[1] + a2[2] + a2[3]);
  }
}

__global__ __launch_bounds__(256) void k_final(const float* __restrict__ z,
                                               const float* __restrict__ ema_es,
                                               const float* __restrict__ noise,
                                               const int* __restrict__ ridx,
                                               const float* __restrict__ embsum,
                                               const float* __restrict__ newcs,
                                               const float* __restrict__ W,
                                               float* __restrict__ out) {
  int gid = blockIdx.x * 256 + threadIdx.x;   // 0 .. KN*64-1
  int k = gid >> 6;
  int d = (gid & 63) << 2;
  float n = W[1];
  float nc = newcs[k];
  float cs_sm = (nc + 1e-5f) / (n + (float)KN * 1e-5f) * n;
  bool dead = (nc / n) < (1.0f / (KN * 10.0f));
  size_t o = (size_t)k * DN + d;
  float4 es = *(const float4*)(ema_es + o);
  float4 s = *(const float4*)(embsum + o);
  float4 nes = make_float4(0.99f * es.x + 0.01f * s.x, 0.99f * es.y + 0.01f * s.y,
                           0.99f * es.z + 0.01f * s.z, 0.99f * es.w + 0.01f * s.w);
  float4 ne = make_float4(nes.x / cs_sm, nes.y / cs_sm, nes.z / cs_sm, nes.w / cs_sm);
  if (dead) {  // wave-uniform (one k per wave)
    int r = ridx[k];
    float4 rz = *(const float4*)(z + (size_t)r * DN + d);
    float4 rn = *(const float4*)(noise + o);
    nes = make_float4(rz.x + rn.x, rz.y + rn.y, rz.z + rn.z, rz.w + rn.w);
    ne = nes;
  }
  float* oe = out + O_EMB + o;   // 8B-aligned region -> float2 stores
  *(float2*)(oe) = make_float2(ne.x, ne.y);
  *(float2*)(oe + 2) = make_float2(ne.z, ne.w);
  float* os = out + O_ES + o;
  *(float2*)(os) = make_float2(nes.x, nes.y);
  *(float2*)(os + 2) = make_float2(nes.z, nes.w);
  if ((gid & 63) == 0) out[O_CS + k] = dead ? 1.0f : nc;
  if (gid == 0) {
    out[O_LOSS] = 0.25f * W[0] * (1.0f / 8388608.0f);
    out[O_PERP] = expf(-W[2]);
  }
}

extern "C" void kernel_launch(void* const* d_in, const int* in_sizes, int n_in,
                              void* d_out, int out_size, void* d_ws, size_t ws_size,
                              hipStream_t stream) {
  const float* z = (const float*)d_in[0];
  const float* emb = (const float*)d_in[1];
  const float* ema_cs = (const float*)d_in[2];
  const float* ema_es = (const float*)d_in[3];
  const float* noise = (const float*)d_in[4];
  const int* ridx = (const int*)d_in[5];
  float* out = (float*)d_out;

  // ws layout (floats): W[8], cluster[KN], embsum[KN*DN], newcs[KN],
  // enorm[KN], then best[BN] (u64, 8B aligned)
  float* W = (float*)d_ws;
  float* cluster = W + 8;
  float* embsum = cluster + KN;
  float* newcs = embsum + (size_t)KN * DN;
  float* enorm = newcs + KN;
  u64* best = (u64*)(enorm + KN);

  // fp16 packed-split scratch in d_out regions overwritten later:
  //  z_q region holds zh|zl (exactly BN*DN*4 B); O_EMB(+2 for 16B align)
  //  holds eh|el (8B spill into O_CS, rewritten by k_final)
  half_t* zh = (half_t*)out;
  half_t* zl = zh + (size_t)BN * DN;
  half_t* eh = (half_t*)(out + O_EMB + 2);
  half_t* el = eh + (size_t)KN * DN;

  hipMemsetAsync(d_ws, 0,
                 (size_t)(8 + KN + (size_t)KN * DN) * sizeof(float), stream);
  hipMemsetAsync(best, 0xFF, (size_t)BN * sizeof(u64), stream);

  k_split<<<dim3(BN / 128, 16), 256, 0, stream>>>(z, zh, zl);
  k_split<<<dim3(KN / 128, 16), 256, 0, stream>>>(emb, eh, el);
  k_enorm<<<KN / 4, 256, 0, stream>>>(emb, enorm);
  k_dist<<<dim3(KN / 128, BN / 128), 256, 0, stream>>>(eh, el, zh, zl, enorm,
                                                       best);
  k_gather<<<BN / 4, 256, 0, stream>>>(z, emb, best, out, W, cluster, embsum);
  k_ema<<<KN / 256, 256, 0, stream>>>(ema_cs, cluster, newcs, W);
  k_final<<<(KN * 64) / 256, 256, 0, stream>>>(z, ema_es, noise, ridx, embsum,
                                               newcs, W, out);
}